// Round 10
// baseline (8174.497 us; speedup 1.0000x reference)
//
#include <hip/hip_runtime.h>
#include <float.h>

#define V 50000
#define E 100
#define H 512
#define T 200
#define B 256
#define NC 5
#define K0 640            // layer0 concat-K: 128 (emb pad) + 512
#define K1 1024           // layer1 concat-K: 512 + 512
#define NH (B * H)        // 131072
#define NW0 (2048 * K0)
#define NW1 (2048 * K1)
#define LOSC 4096.0f      // lo-plane scale (2^12) keeps lo out of fp16 denormals
#define ILOSC (1.0f / 4096.0f)
#define NBLK 512          // 2 blocks / CU
#define HSLOT (NH * 2)    // halves per h slot (hi+lo interleaved records)

typedef _Float16 half8 __attribute__((ext_vector_type(8)));
typedef float floatx4 __attribute__((ext_vector_type(4)));
typedef unsigned long long u64;

// ---------------- activations ----------------
__device__ __forceinline__ float fsig(float x)  { return 1.f / (1.f + __expf(-x)); }
__device__ __forceinline__ float ftanh(float x) { return 1.f - 2.f / (__expf(2.f * x) + 1.f); }

// ---------------- sc1 store (coherence point). h WRITES only. ----------------
// h READS are PLAIN (L2/L1-cached, 64x dedup'd per XCD). Correctness: every
// block issues an agent-acquire fence (buffer_inv) after every barrier, before
// its next reads; h slots alternate parity so no line is read in the same step
// it is written -> no stale copy can ever be observed.
__device__ __forceinline__ void st_u64_cc(void* p, u64 v) {
    __hip_atomic_store((u64*)p, v, __ATOMIC_RELAXED, __HIP_MEMORY_SCOPE_AGENT);
}

// ---------------- workspace map ----------------
// h layout (hi/lo interleaved): h[slot][b][H/8] records of 16 halves:
//   halves 0..7 = hi of 8-j chunk, 8..15 = lo.  (r3/r8/r9 proven layout)
struct WS {
    _Float16 *W0h, *W0l, *W1h, *W1l;   // [2048][K] split planes, c = j*4+g
    _Float16 *h0, *h1;                 // [2 slots][B][H/8][16] interleaved
    float *hmax;                       // [B][H]
    int *last;                         // [B]
    unsigned *arr;                     // [NBLK] arrival words (sc1)
    unsigned *gen;                     // generation word (sc1, own line)
};
__device__ __host__ inline WS wsmap(char* p) {
    WS w;
    w.W0h = (_Float16*)p;  p += (size_t)NW0 * 2;
    w.W0l = (_Float16*)p;  p += (size_t)NW0 * 2;
    w.W1h = (_Float16*)p;  p += (size_t)NW1 * 2;
    w.W1l = (_Float16*)p;  p += (size_t)NW1 * 2;
    w.h0  = (_Float16*)p;  p += (size_t)2 * HSLOT * 2;   // 1 MiB
    w.h1  = (_Float16*)p;  p += (size_t)2 * HSLOT * 2;   // 1 MiB
    w.hmax = (float*)p;    p += (size_t)NH * 4;
    w.last = (int*)p;      p += (size_t)B * 4;
    w.arr  = (unsigned*)p;                 // +0 .. +2047  (512 words)
    w.gen  = (unsigned*)(p + 2048);        // own line
    return w;
}

// ---------------- prep: split weights into fp16 hi/lo catenated layout ----------------
__global__ void k_prep(const float* __restrict__ Wih0, const float* __restrict__ Whh0,
                       const float* __restrict__ Wih1, const float* __restrict__ Whh1,
                       char* wsraw) {
    WS w = wsmap(wsraw);
    int idx = blockIdx.x * 256 + threadIdx.x;
    if (idx < NW0) {
        int c = idx / K0, k = idx - c * K0;
        int jx = c >> 2, g = c & 3, row = g * H + jx;
        float v = 0.f;
        if (k < 128) { if (k < E) v = Wih0[(size_t)row * E + k]; }
        else           v = Whh0[(size_t)row * H + (k - 128)];
        _Float16 hh = (_Float16)v;
        w.W0h[idx] = hh;
        w.W0l[idx] = (_Float16)((v - (float)hh) * LOSC);
    } else if (idx < NW0 + NW1) {
        int i2 = idx - NW0;
        int c = i2 / K1, k = i2 - c * K1;
        int jx = c >> 2, g = c & 3, row = g * H + jx;
        float v = (k < H) ? Wih1[(size_t)row * H + k]
                          : Whh1[(size_t)row * H + (k - H)];
        _Float16 hh = (_Float16)v;
        w.W1h[i2] = hh;
        w.W1l[i2] = (_Float16)((v - (float)hh) * LOSC);
    }
}

// ---------------- init: zero h planes, last[b], barrier words ----------------
__global__ void k_init(const int* __restrict__ X, char* wsraw) {
    WS w = wsmap(wsraw);
    int i = blockIdx.x * 256 + threadIdx.x;
    if (i < 524288) ((unsigned*)w.h0)[i] = 0u;   // h0,h1 contiguous = 2 MiB
    if (i < 520)    w.arr[i] = 0u;               // arr (512) + gen
    if (i < B) {
        int l = -1;
        const int* xr = X + i * T;
        for (int t = 0; t < T; ++t) if (xr[t] != V) l = t;
        w.last[i] = l;
    }
}

// ---------------- persistent kernel: reg-weights + L2-cached h + per-step inv ----
// 512 blocks (2/CU): block = (cblk 0..127 -> 16 c-rows / 4 j, bblk 0..3 -> 64 b),
// BOTH layers per block per iteration (r9-proven phase order & parity).
// bblk sits in bid&7 so under %8 XCD round-robin each XCD holds ONE bblk ->
// per-XCD h fill ~384 KB/step (graceful 1.5 MB if the mapping differs).
// Per-thread weights: (5+8) kb x 2 planes = 26 half8 = 104 VGPR. acc -> AGPR.
__global__ __launch_bounds__(256, 2) void k_lstm(
    const int* __restrict__ X, const float* __restrict__ emb,
    const float* __restrict__ b0, const float* __restrict__ b1,
    char* __restrict__ wsraw)
{
    __shared__ float red[4 * 64 * 20];   // [wave][64 b][16 c + 4 pad]

    const int tid = threadIdx.x, lane = tid & 63, wq = tid >> 6;
    const int m = lane & 15, qq = lane >> 4;
    const int bid = blockIdx.x;
    const int xid = bid & 7;
    const int bblk = xid >> 1;
    const int cblk = ((xid & 1) << 6) + (bid >> 3);   // 0..127
    const int c0g = cblk * 16, b0gl = bblk * 64, j0g = cblk * 4;

    WS w = wsmap(wsraw);

    // ---- preload this thread's weight fragments into registers (once) ----
    half8 W0hr[5], W0lr[5], W1hr[8], W1lr[8];
#pragma unroll
    for (int i = 0; i < 5; ++i) {
        const size_t ro = (size_t)(c0g + m) * K0 + (wq + 4 * i) * 32 + qq * 8;
        W0hr[i] = *(const half8*)(w.W0h + ro);
        W0lr[i] = *(const half8*)(w.W0l + ro);
    }
#pragma unroll
    for (int i = 0; i < 8; ++i) {
        const size_t ro = (size_t)(c0g + m) * K1 + (wq + 4 * i) * 32 + qq * 8;
        W1hr[i] = *(const half8*)(w.W1h + ro);
        W1lr[i] = *(const half8*)(w.W1l + ro);
    }

    // ---- per-bs h record row bases (loop-invariant) ----
    size_t rowb[4];
#pragma unroll
    for (int bs = 0; bs < 4; ++bs)
        rowb[bs] = (size_t)(b0gl + bs * 16 + m) * (H / 8) * 16;

    // ---- epilogue (wave 0, 64 threads): thread owns (b = tid, 4 j) ----
    const int bg_e = b0gl + lane;
    const int hioff = (cblk & 1) * 4;
    const size_t recoff = ((size_t)bg_e * (H / 8) + (j0g >> 3)) * 16;
    float c0r[4] = {0.f, 0.f, 0.f, 0.f};
    float c1r[4] = {0.f, 0.f, 0.f, 0.f};
    float hmr[4] = {-FLT_MAX, -FLT_MAX, -FLT_MAX, -FLT_MAX};
    const int lastb = w.last[bg_e];

    for (int t = 0; t <= T; ++t) {
        // ================= phase L0(t): g = W0 * [emb(x_t); h0(t-1)] =================
        if (t < T) {
            floatx4 acc0[4], acc1[4];
#pragma unroll
            for (int i = 0; i < 4; ++i) {
                floatx4 z = {0.f, 0.f, 0.f, 0.f};
                acc0[i] = z; acc1[i] = z;
            }
            half8 Bh[2][4], Bl[2][4];
            {   // kb = wq (<4): emb region, convert on the fly
                const int ko = wq * 32 + qq * 8;
#pragma unroll
                for (int bs = 0; bs < 4; ++bs) {
                    int er = X[(b0gl + bs * 16 + m) * T + t];
                    const float* p = emb + (size_t)er * E;
                    float4 fa = make_float4(0.f,0.f,0.f,0.f), fb = fa;
                    if (ko <= 96) fa = *(const float4*)(p + ko);
                    if (ko <= 92) fb = *(const float4*)(p + ko + 4);
                    float e[8] = {fa.x,fa.y,fa.z,fa.w, fb.x,fb.y,fb.z,fb.w};
                    half8 hh, hl;
#pragma unroll
                    for (int u = 0; u < 8; ++u) {
                        _Float16 hv = (_Float16)e[u];
                        hh[u] = hv;
                        hl[u] = (_Float16)((e[u] - (float)hv) * LOSC);
                    }
                    Bh[0][bs] = hh; Bl[0][bs] = hl;
                }
            }
            const _Float16* x0 = w.h0 + (size_t)((t + 1) & 1) * HSLOT;
#pragma unroll
            for (int i = 0; i < 5; ++i) {
                const int cur = i & 1;
                if (i + 1 < 5) {
                    const int ch = ((wq + 4 * (i + 1)) * 32 + qq * 8 - 128) >> 3;
#pragma unroll
                    for (int bs = 0; bs < 4; ++bs) {
                        const _Float16* bp = x0 + rowb[bs] + ch * 16;
                        Bh[cur ^ 1][bs] = *(const half8*)(bp);
                        Bl[cur ^ 1][bs] = *(const half8*)(bp + 8);
                    }
                }
#pragma unroll
                for (int bs = 0; bs < 4; ++bs) {
                    acc0[bs] = __builtin_amdgcn_mfma_f32_16x16x32_f16(W0hr[i], Bh[cur][bs], acc0[bs], 0, 0, 0);
                    acc1[bs] = __builtin_amdgcn_mfma_f32_16x16x32_f16(W0hr[i], Bl[cur][bs], acc1[bs], 0, 0, 0);
                    acc1[bs] = __builtin_amdgcn_mfma_f32_16x16x32_f16(W0lr[i], Bh[cur][bs], acc1[bs], 0, 0, 0);
                }
            }
#pragma unroll
            for (int bs = 0; bs < 4; ++bs) {
                floatx4 v = acc0[bs] + acc1[bs] * ILOSC;
                *(floatx4*)&red[((wq * 64 + bs * 16 + m) * 20 + qq * 4)] = v;
            }
            __syncthreads();
            if (tid < 64) {
                _Float16* o = w.h0 + (size_t)(t & 1) * HSLOT;
                float4 bvi = *(const float4*)&b0[0 * H + j0g];
                float4 bvf = *(const float4*)&b0[1 * H + j0g];
                float4 bvg = *(const float4*)&b0[2 * H + j0g];
                float4 bvo = *(const float4*)&b0[3 * H + j0g];
                const float bi[4] = {bvi.x, bvi.y, bvi.z, bvi.w};
                const float bf[4] = {bvf.x, bvf.y, bvf.z, bvf.w};
                const float bg[4] = {bvg.x, bvg.y, bvg.z, bvg.w};
                const float bo[4] = {bvo.x, bvo.y, bvo.z, bvo.w};
                union { _Float16 h[4]; u64 uu; } ph, pl;
#pragma unroll
                for (int u = 0; u < 4; ++u) {
                    floatx4 g = *(floatx4*)&red[(0 * 64 + lane) * 20 + u * 4];
#pragma unroll
                    for (int q2 = 1; q2 < 4; ++q2)
                        g += *(floatx4*)&red[((q2 * 64 + lane) * 20 + u * 4)];
                    float ig = fsig (g.x + bi[u]);
                    float fg = fsig (g.y + bf[u]);
                    float gg = ftanh(g.z + bg[u]);
                    float og = fsig (g.w + bo[u]);
                    float cn = fg * c0r[u] + ig * gg;
                    float hn = og * ftanh(cn);
                    c0r[u] = cn;
                    _Float16 hh = (_Float16)hn;
                    ph.h[u] = hh;
                    pl.h[u] = (_Float16)((hn - (float)hh) * LOSC);
                }
                st_u64_cc(o + recoff + hioff,     ph.uu);
                st_u64_cc(o + recoff + 8 + hioff, pl.uu);
            }
            __syncthreads();
        }

        // ================= phase L1(t-1): g = W1 * [h0(t-1); h1(t-2)] =================
        if (t >= 1) {
            const int tt = t - 1;
            floatx4 acc0[4], acc1[4];
#pragma unroll
            for (int i = 0; i < 4; ++i) {
                floatx4 z = {0.f, 0.f, 0.f, 0.f};
                acc0[i] = z; acc1[i] = z;
            }
            half8 Bh[2][4], Bl[2][4];
            const _Float16* y0 = w.h0 + (size_t)(tt & 1) * HSLOT;
            const _Float16* y1 = w.h1 + (size_t)((tt + 1) & 1) * HSLOT;
            {   // kb = wq (<16): y0
                const int ch = (wq * 32 + qq * 8) >> 3;
#pragma unroll
                for (int bs = 0; bs < 4; ++bs) {
                    const _Float16* bp = y0 + rowb[bs] + ch * 16;
                    Bh[0][bs] = *(const half8*)(bp);
                    Bl[0][bs] = *(const half8*)(bp + 8);
                }
            }
#pragma unroll
            for (int i = 0; i < 8; ++i) {
                const int cur = i & 1;
                if (i + 1 < 8) {
                    const int kbn = wq + 4 * (i + 1);
                    const int kon = kbn * 32 + qq * 8;
                    const _Float16* sx = (kbn < 16) ? y0 : y1;
                    const int ch = ((kbn < 16) ? kon : kon - 512) >> 3;
#pragma unroll
                    for (int bs = 0; bs < 4; ++bs) {
                        const _Float16* bp = sx + rowb[bs] + ch * 16;
                        Bh[cur ^ 1][bs] = *(const half8*)(bp);
                        Bl[cur ^ 1][bs] = *(const half8*)(bp + 8);
                    }
                }
#pragma unroll
                for (int bs = 0; bs < 4; ++bs) {
                    acc0[bs] = __builtin_amdgcn_mfma_f32_16x16x32_f16(W1hr[i], Bh[cur][bs], acc0[bs], 0, 0, 0);
                    acc1[bs] = __builtin_amdgcn_mfma_f32_16x16x32_f16(W1hr[i], Bl[cur][bs], acc1[bs], 0, 0, 0);
                    acc1[bs] = __builtin_amdgcn_mfma_f32_16x16x32_f16(W1lr[i], Bh[cur][bs], acc1[bs], 0, 0, 0);
                }
            }
#pragma unroll
            for (int bs = 0; bs < 4; ++bs) {
                floatx4 v = acc0[bs] + acc1[bs] * ILOSC;
                *(floatx4*)&red[((wq * 64 + bs * 16 + m) * 20 + qq * 4)] = v;
            }
            __syncthreads();
            if (tid < 64) {
                _Float16* o = w.h1 + (size_t)(tt & 1) * HSLOT;
                float4 bvi = *(const float4*)&b1[0 * H + j0g];
                float4 bvf = *(const float4*)&b1[1 * H + j0g];
                float4 bvg = *(const float4*)&b1[2 * H + j0g];
                float4 bvo = *(const float4*)&b1[3 * H + j0g];
                const float bi[4] = {bvi.x, bvi.y, bvi.z, bvi.w};
                const float bf[4] = {bvf.x, bvf.y, bvf.z, bvf.w};
                const float bg[4] = {bvg.x, bvg.y, bvg.z, bvg.w};
                const float bo[4] = {bvo.x, bvo.y, bvo.z, bvo.w};
                const bool keep = (tt <= lastb);
                union { _Float16 h[4]; u64 uu; } ph, pl;
#pragma unroll
                for (int u = 0; u < 4; ++u) {
                    floatx4 g = *(floatx4*)&red[(0 * 64 + lane) * 20 + u * 4];
#pragma unroll
                    for (int q2 = 1; q2 < 4; ++q2)
                        g += *(floatx4*)&red[((q2 * 64 + lane) * 20 + u * 4)];
                    float ig = fsig (g.x + bi[u]);
                    float fg = fsig (g.y + bf[u]);
                    float gg = ftanh(g.z + bg[u]);
                    float og = fsig (g.w + bo[u]);
                    float cn = fg * c1r[u] + ig * gg;
                    float hn = og * ftanh(cn);
                    c1r[u] = cn;
                    if (keep) hmr[u] = fmaxf(hmr[u], hn);
                    _Float16 hh = (_Float16)hn;
                    ph.h[u] = hh;
                    pl.h[u] = (_Float16)((hn - (float)hh) * LOSC);
                }
                st_u64_cc(o + recoff + hioff,     ph.uu);
                st_u64_cc(o + recoff + 8 + hioff, pl.uu);
            }
            __syncthreads();
        }

        // ================= grid barrier + acquire-inv (plain-h correctness) ========
        if (t < T) {
            const unsigned tgt = (unsigned)(t + 1);
            asm volatile("s_waitcnt vmcnt(0)" ::: "memory");   // sc1 h-stores ACKED at MALL
            __syncthreads();
            if (tid == 0)
                __hip_atomic_store(&w.arr[bid], tgt, __ATOMIC_RELAXED, __HIP_MEMORY_SCOPE_AGENT);
            if (bid == 0) {
                if (tid < 64) {
                    for (;;) {
                        bool ok = true;
#pragma unroll
                        for (int k2 = 0; k2 < 8; ++k2) {
                            unsigned f = __hip_atomic_load(&w.arr[tid + 64 * k2],
                                           __ATOMIC_RELAXED, __HIP_MEMORY_SCOPE_AGENT);
                            ok &= (f >= tgt);
                        }
                        if (__all(ok)) break;
                        __builtin_amdgcn_s_sleep(2);
                    }
                    if (tid == 0)
                        __hip_atomic_store(w.gen, tgt, __ATOMIC_RELAXED, __HIP_MEMORY_SCOPE_AGENT);
                }
            } else {
                if (tid == 0) {
                    while (__hip_atomic_load(w.gen, __ATOMIC_RELAXED, __HIP_MEMORY_SCOPE_AGENT) < tgt)
                        __builtin_amdgcn_s_sleep(4);
                }
            }
            // invalidate this CU's L1 + XCD L2 so next step's plain h reads are fresh.
            // (Safe even if issued before gen is observed: nobody reads a slot in the
            // step it is written — parity separation — so no stale value can re-cache.)
            __builtin_amdgcn_fence(__ATOMIC_ACQUIRE, "agent");
            __syncthreads();
        }
    }

    // ---- write out register-resident maxpool state ----
    if (tid < 64)
        *(float4*)(w.hmax + (size_t)bg_e * H + j0g) =
            make_float4(hmr[0], hmr[1], hmr[2], hmr[3]);
}

// ---------------- final: logits ----------------
__global__ __launch_bounds__(64) void k_out(const float* __restrict__ hmax,
                                            const float* __restrict__ Wout,
                                            const float* __restrict__ bout,
                                            float* __restrict__ out) {
    const int b = blockIdx.x * 64 + threadIdx.x;
    float a[NC] = {0.f, 0.f, 0.f, 0.f, 0.f};
    const float* hm = hmax + (size_t)b * H;
    for (int j = 0; j < H; ++j) {
        float hv = hm[j];
#pragma unroll
        for (int cls = 0; cls < NC; ++cls)
            a[cls] = fmaf(hv, Wout[cls * H + j], a[cls]);
    }
#pragma unroll
    for (int cls = 0; cls < NC; ++cls)
        out[b * NC + cls] = a[cls] + bout[cls];
}

// ---------------- launch ----------------
extern "C" void kernel_launch(void* const* d_in, const int* in_sizes, int n_in,
                              void* d_out, int out_size, void* d_ws, size_t ws_size,
                              hipStream_t stream) {
    const int*   X    = (const int*)  d_in[0];
    const float* emb  = (const float*)d_in[1];
    const float* Wih0 = (const float*)d_in[2];
    const float* Whh0 = (const float*)d_in[3];
    const float* b0   = (const float*)d_in[4];
    const float* Wih1 = (const float*)d_in[5];
    const float* Whh1 = (const float*)d_in[6];
    const float* b1   = (const float*)d_in[7];
    const float* Wout = (const float*)d_in[8];
    const float* bout = (const float*)d_in[9];
    float* out = (float*)d_out;
    char* ws = (char*)d_ws;
    WS w = wsmap(ws);

    k_prep<<<(NW0 + NW1 + 255) / 256, 256, 0, stream>>>(Wih0, Whh0, Wih1, Whh1, ws);
    k_init<<<2048, 256, 0, stream>>>(X, ws);

    {
        void* args[] = {(void*)&X, (void*)&emb, (void*)&b0, (void*)&b1, (void*)&ws};
        hipError_t e = hipLaunchCooperativeKernel((const void*)k_lstm, dim3(NBLK), dim3(256),
                                                  args, 0, stream);
        if (e != hipSuccess) {
            // 512 blocks at 2/CU (forced by launch_bounds) fill the chip exactly;
            // co-residency holds in practice.
            k_lstm<<<NBLK, 256, 0, stream>>>(X, emb, b0, b1, ws);
        }
    }

    k_out<<<4, 64, 0, stream>>>(w.hmax, Wout, bout, out);
}

// Round 11
// 4907.821 us; speedup vs baseline: 1.6656x; 1.6656x over previous
//
#include <hip/hip_runtime.h>
#include <float.h>

#define V 50000
#define E 100
#define H 512
#define T 200
#define B 256
#define NC 5
#define K0 640            // layer0 concat-K: 128 (emb pad) + 512
#define K1 1024           // layer1 concat-K: 512 + 512
#define NH (B * H)        // 131072
#define NW0 (2048 * K0)
#define NW1 (2048 * K1)
#define LOSC 4096.0f      // lo-plane scale (2^12) keeps lo out of fp16 denormals
#define ILOSC (1.0f / 4096.0f)

typedef _Float16 half8 __attribute__((ext_vector_type(8)));
typedef float floatx4 __attribute__((ext_vector_type(4)));

// ---------------- activations ----------------
__device__ __forceinline__ float fsig(float x)  { return 1.f / (1.f + __expf(-x)); }
__device__ __forceinline__ float ftanh(float x) { return 1.f - 2.f / (__expf(2.f * x) + 1.f); }

// ---------------- workspace map (round-0 proven) ----------------
struct WS {
    _Float16 *W0h, *W0l, *W1h, *W1l;   // [2048][K] split planes, c = j*4+g
    _Float16 *h0h, *h0l, *h1h, *h1l;   // [2 slots][B][H] split planes (lo pre-scaled)
    float *c0, *c1, *hmax;             // [B][H]
    int *last;
};
__device__ __host__ inline WS wsmap(char* p) {
    WS w;
    w.W0h = (_Float16*)p;  p += (size_t)NW0 * 2;
    w.W0l = (_Float16*)p;  p += (size_t)NW0 * 2;
    w.W1h = (_Float16*)p;  p += (size_t)NW1 * 2;
    w.W1l = (_Float16*)p;  p += (size_t)NW1 * 2;
    w.h0h = (_Float16*)p;  p += (size_t)2 * NH * 2;
    w.h0l = (_Float16*)p;  p += (size_t)2 * NH * 2;
    w.h1h = (_Float16*)p;  p += (size_t)2 * NH * 2;
    w.h1l = (_Float16*)p;  p += (size_t)2 * NH * 2;
    w.c0   = (float*)p;    p += (size_t)NH * 4;
    w.c1   = (float*)p;    p += (size_t)NH * 4;
    w.hmax = (float*)p;    p += (size_t)NH * 4;
    w.last = (int*)p;
    return w;
}

// ---------------- prep: split weights into fp16 hi/lo catenated layout ----------------
__global__ void k_prep(const float* __restrict__ Wih0, const float* __restrict__ Whh0,
                       const float* __restrict__ Wih1, const float* __restrict__ Whh1,
                       char* wsraw) {
    WS w = wsmap(wsraw);
    int idx = blockIdx.x * 256 + threadIdx.x;
    if (idx < NW0) {
        int c = idx / K0, k = idx - c * K0;
        int jx = c >> 2, g = c & 3, row = g * H + jx;
        float v = 0.f;
        if (k < 128) { if (k < E) v = Wih0[(size_t)row * E + k]; }
        else           v = Whh0[(size_t)row * H + (k - 128)];
        _Float16 hh = (_Float16)v;
        w.W0h[idx] = hh;
        w.W0l[idx] = (_Float16)((v - (float)hh) * LOSC);
    } else if (idx < NW0 + NW1) {
        int i2 = idx - NW0;
        int c = i2 / K1, k = i2 - c * K1;
        int jx = c >> 2, g = c & 3, row = g * H + jx;
        float v = (k < H) ? Wih1[(size_t)row * H + k]
                          : Whh1[(size_t)row * H + (k - H)];
        _Float16 hh = (_Float16)v;
        w.W1h[i2] = hh;
        w.W1l[i2] = (_Float16)((v - (float)hh) * LOSC);
    }
}

// ---------------- init: zero states, hmax=-FLT_MAX, last[b] ----------------
__global__ void k_init(const int* __restrict__ X, char* wsraw) {
    WS w = wsmap(wsraw);
    int i = blockIdx.x * 256 + threadIdx.x;
    if (i < 524288)                     ((unsigned*)w.h0h)[i] = 0u;        // all h planes
    else if (i < 524288 + 262144)       ((unsigned*)w.c0)[i - 524288] = 0u; // c0,c1
    else if (i < 524288 + 262144 + NH)  w.hmax[i - 786432] = -FLT_MAX;
    if (i < B) {
        int l = -1;
        const int* xr = X + i * T;
        for (int t = 0; t < T; ++t) if (xr[t] != V) l = t;
        w.last[i] = l;
    }
}

// ---------------- K-quarter MFMA loop (per wave), cs=2 (32 c-rows/block) ----------
template <int LAYER>
__device__ __forceinline__ void run_mm(
    int t, const int* __restrict__ X, const float* __restrict__ emb,
    const _Float16* __restrict__ Wh, const _Float16* __restrict__ Wl,
    const _Float16* __restrict__ xh0, const _Float16* __restrict__ xl0,
    const _Float16* __restrict__ xh1, const _Float16* __restrict__ xl1,
    int c0g, int b0gl, int m, int qq, int wq,
    floatx4 (&acc0)[8], floatx4 (&acc1)[8])
{
    const int KT  = LAYER ? K1 : K0;
    const int NKB = LAYER ? 8 : 5;    // k-blocks of 32 per wave (kb = wq + 4*i)
    int erow[4];
    if (LAYER == 0) {
#pragma unroll
        for (int bs = 0; bs < 4; ++bs)
            erow[bs] = X[(b0gl + bs * 16 + m) * T + t];
    }
    half8 A_h[2][2], A_l[2][2], B_h[2][4], B_l[2][4];

    auto ldkb = [&](int kb, int buf) {
        const int ko = kb * 32 + qq * 8;
#pragma unroll
        for (int cs = 0; cs < 2; ++cs) {
            const size_t ro = (size_t)(c0g + cs * 16 + m) * KT + ko;
            A_h[buf][cs] = *(const half8*)(Wh + ro);
            A_l[buf][cs] = *(const half8*)(Wl + ro);
        }
        if (LAYER == 0 && kb < 4) {            // embedding part, convert on the fly
#pragma unroll
            for (int bs = 0; bs < 4; ++bs) {
                const float* er = emb + (size_t)erow[bs] * E;
                float4 fa = make_float4(0.f,0.f,0.f,0.f), fb = fa;
                if (ko <= 96) fa = *(const float4*)(er + ko);
                if (ko <= 92) fb = *(const float4*)(er + ko + 4);
                float e[8] = {fa.x,fa.y,fa.z,fa.w, fb.x,fb.y,fb.z,fb.w};
                half8 hh, hl;
#pragma unroll
                for (int u = 0; u < 8; ++u) {
                    _Float16 hv = (_Float16)e[u];
                    hh[u] = hv;
                    hl[u] = (_Float16)((e[u] - (float)hv) * LOSC);
                }
                B_h[buf][bs] = hh; B_l[buf][bs] = hl;
            }
        } else {
            const _Float16 *sh, *sl; int kk;
            if (LAYER == 0)      { sh = xh0; sl = xl0; kk = ko - 128; }
            else if (kb < 16)    { sh = xh0; sl = xl0; kk = ko; }
            else                 { sh = xh1; sl = xl1; kk = ko - 512; }
#pragma unroll
            for (int bs = 0; bs < 4; ++bs) {
                const size_t ro = (size_t)(b0gl + bs * 16 + m) * H + kk;
                B_h[buf][bs] = *(const half8*)(sh + ro);
                B_l[buf][bs] = *(const half8*)(sl + ro);
            }
        }
    };

    ldkb(wq, 0);
#pragma unroll
    for (int i = 0; i < NKB; ++i) {
        const int cur = i & 1;
        if (i + 1 < NKB) ldkb(wq + 4 * (i + 1), cur ^ 1);   // prefetch next k-block
#pragma unroll
        for (int cs = 0; cs < 2; ++cs)
#pragma unroll
            for (int bs = 0; bs < 4; ++bs) {
                const int ti = cs * 4 + bs;
                acc0[ti] = __builtin_amdgcn_mfma_f32_16x16x32_f16(A_h[cur][cs], B_h[cur][bs], acc0[ti], 0, 0, 0);
                acc1[ti] = __builtin_amdgcn_mfma_f32_16x16x32_f16(A_h[cur][cs], B_l[cur][bs], acc1[ti], 0, 0, 0);
                acc1[ti] = __builtin_amdgcn_mfma_f32_16x16x32_f16(A_l[cur][cs], B_h[cur][bs], acc1[ti], 0, 0, 0);
            }
    }
}

// ---------------- fused step: 512 blocks (2/CU), block = (layer, bblk, cblk) ------
// bid = ((layer*4 + bblk)*8 + chi)*8 + xcd, cblk = chi*8+xcd in 0..63 (32 c-rows).
// Halved c-tile -> acc 64 VGPR, LDS 36.9 KB -> 2 blocks/CU co-resident (8 waves/CU).
__global__ __launch_bounds__(256, 2) void k_step(
    int t, const int* __restrict__ X, const float* __restrict__ emb,
    const float* __restrict__ b0, const float* __restrict__ b1,
    char* __restrict__ wsraw)
{
    extern __shared__ float red[];    // [4 waves][64 b][36]  (c-minor, +4 pad)

    const int tid = threadIdx.x, lane = tid & 63, wq = tid >> 6;
    const int m = lane & 15, qq = lane >> 4;
    const int bid = blockIdx.x;
    const int xcd = bid & 7, chi = (bid >> 3) & 7;
    const int bblk = (bid >> 6) & 3, layer = bid >> 8;
    const int cblk = chi * 8 + xcd;
    if (layer == 0 && t >= T) return;
    if (layer == 1 && t < 1)  return;
    const int tt = t - 1;
    const int c0g = cblk * 32, b0gl = bblk * 64, j0g = cblk * 8;

    WS w = wsmap(wsraw);

    floatx4 acc0[8], acc1[8];
#pragma unroll
    for (int i = 0; i < 8; ++i) {
        floatx4 z = {0.f, 0.f, 0.f, 0.f};
        acc0[i] = z; acc1[i] = z;
    }

    if (layer == 0)
        run_mm<0>(t, X, emb, w.W0h, w.W0l,
                  w.h0h + (size_t)((t + 1) & 1) * NH, w.h0l + (size_t)((t + 1) & 1) * NH,
                  nullptr, nullptr, c0g, b0gl, m, qq, wq, acc0, acc1);
    else
        run_mm<1>(tt, X, emb, w.W1h, w.W1l,
                  w.h0h + (size_t)(tt & 1) * NH, w.h0l + (size_t)(tt & 1) * NH,
                  w.h1h + (size_t)((tt + 1) & 1) * NH, w.h1l + (size_t)((tt + 1) & 1) * NH,
                  c0g, b0gl, m, qq, wq, acc0, acc1);

    // ---- fold lo-acc, dump k-quarter partials ----
#pragma unroll
    for (int cs = 0; cs < 2; ++cs)
#pragma unroll
        for (int bs = 0; bs < 4; ++bs) {
            floatx4 v = acc0[cs * 4 + bs] + acc1[cs * 4 + bs] * ILOSC;
            const int bl = bs * 16 + m, cl = cs * 16 + qq * 4;
            *(floatx4*)&red[((wq * 64 + bl) * 36 + cl)] = v;
        }
    __syncthreads();

    // ---- reduce 4 quarters + epilogue; wave wq owns b-strip [wq*16, wq*16+16) ----
    const int jj = lane & 7, bq = lane >> 3;
    const int j = j0g + jj;
    const float* bias = layer ? b1 : b0;
    const float bv0 = bias[0 * H + j], bv1 = bias[1 * H + j];
    const float bv2 = bias[2 * H + j], bv3 = bias[3 * H + j];
    float* cst = layer ? w.c1 : w.c0;
    _Float16* oh = layer ? (w.h1h + (size_t)(tt & 1) * NH) : (w.h0h + (size_t)(t & 1) * NH);
    _Float16* ol = layer ? (w.h1l + (size_t)(tt & 1) * NH) : (w.h0l + (size_t)(t & 1) * NH);

#pragma unroll
    for (int bi = 0; bi < 2; ++bi) {
        const int bl = wq * 16 + bq + 8 * bi;     // 8 lanes (jj) share this b
        const int bg = b0gl + bl;
        floatx4 g = *(floatx4*)&red[((0 * 64 + bl) * 36 + jj * 4)];
#pragma unroll
        for (int q2 = 1; q2 < 4; ++q2)
            g += *(floatx4*)&red[((q2 * 64 + bl) * 36 + jj * 4)];
        float ig = fsig (g.x + bv0);
        float fg = fsig (g.y + bv1);
        float gg = ftanh(g.z + bv2);
        float og = fsig (g.w + bv3);
        float cold = cst[(size_t)bg * H + j];
        float cn = fg * cold + ig * gg;
        float hn = og * ftanh(cn);
        cst[(size_t)bg * H + j] = cn;
        _Float16 hh = (_Float16)hn;
        oh[(size_t)bg * H + j] = hh;
        ol[(size_t)bg * H + j] = (_Float16)((hn - (float)hh) * LOSC);
        if (layer == 1 && tt <= w.last[bg]) {
            float* hp = w.hmax + (size_t)bg * H + j;
            *hp = fmaxf(*hp, hn);
        }
    }
}

// ---------------- final: logits[b][cls] = sum_j hmax[b][j] * Wout[cls][j] + bout ----
__global__ __launch_bounds__(64) void k_out(const float* __restrict__ hmax,
                                            const float* __restrict__ Wout,
                                            const float* __restrict__ bout,
                                            float* __restrict__ out) {
    const int b = blockIdx.x * 64 + threadIdx.x;
    float a[NC] = {0.f, 0.f, 0.f, 0.f, 0.f};
    const float* hm = hmax + (size_t)b * H;
    for (int j = 0; j < H; ++j) {
        float hv = hm[j];
#pragma unroll
        for (int cls = 0; cls < NC; ++cls)
            a[cls] = fmaf(hv, Wout[cls * H + j], a[cls]);
    }
#pragma unroll
    for (int cls = 0; cls < NC; ++cls)
        out[b * NC + cls] = a[cls] + bout[cls];
}

// ---------------- launch ----------------
extern "C" void kernel_launch(void* const* d_in, const int* in_sizes, int n_in,
                              void* d_out, int out_size, void* d_ws, size_t ws_size,
                              hipStream_t stream) {
    const int*   X    = (const int*)  d_in[0];
    const float* emb  = (const float*)d_in[1];
    const float* Wih0 = (const float*)d_in[2];
    const float* Whh0 = (const float*)d_in[3];
    const float* b0   = (const float*)d_in[4];
    const float* Wih1 = (const float*)d_in[5];
    const float* Whh1 = (const float*)d_in[6];
    const float* b1   = (const float*)d_in[7];
    const float* Wout = (const float*)d_in[8];
    const float* bout = (const float*)d_in[9];
    float* out = (float*)d_out;
    char* ws = (char*)d_ws;
    WS w = wsmap(ws);

    k_prep<<<(NW0 + NW1 + 255) / 256, 256, 0, stream>>>(Wih0, Whh0, Wih1, Whh1, ws);
    k_init<<<(524288 + 262144 + NH + 255) / 256, 256, 0, stream>>>(X, ws);

    // Dispatch t computes layer0(t) and layer1(t-1); t = 0..T inclusive.
    for (int t = 0; t <= T; ++t) {
        k_step<<<512, 256, 4 * 64 * 36 * sizeof(float), stream>>>(t, X, emb, b0, b1, ws);
    }

    k_out<<<4, 64, 0, stream>>>(w.hmax, Wout, bout, out);
}